// Round 9
// baseline (759.781 us; speedup 1.0000x reference)
//
#include <hip/hip_runtime.h>
#include <math.h>

#define HIDDEN 16
#define CIN 5
#define BB 8
#define TT 12
#define HH 256
#define WW 256
// legacy (per-step fallback) tile geometry
#define TX 32
#define TY 8
#define HALO_X 34
#define HALO_Y 10
#define NPX (HALO_X * HALO_Y)
#define STRIDE 40
// temporal-blocked persistent geometry: 32x8 tiles, Tb=2 steps per visit
#define PTX 32
#define PTY 8
#define SHX 36                  // staged region: halo 2
#define SHY 12
#define SNPX (SHX * SHY)        // 432 px
#define THX 34                  // intermediate region: halo 1
#define THY 10
#define TNPX (THX * THY)        // 340 px
#define RS 24                   // shorts per px: h16|x8 (48 B, 16B-aligned)
#define T_OFF (SNPX * RS)       // 10368
#define ZOFF (T_OFF + TNPX * RS)   // 18528  zero block (quad3 K-pad reads)
#define DOFF (ZOFF + 8)            // 18536  dump row for clamped writes
#define SMSH (DOFF + 24)           // 18560 shorts = 37120 B -> 4 blocks/CU
#define NSS (TT / 2)            // 6 super-steps
#define NTILES 2048
#define NBLK 1024               // 4 blocks/CU x 256 CU, 2 tiles each
#define XSTEP (HH * WW * 8)
// compressed W table: [tap][gate][lane48][8] + 8-short zero pad (quad3 = 0)
#define WSH (9 * 4 * 48 * 8)
#define WSH_PAD (WSH + 8)

typedef __attribute__((ext_vector_type(8))) short bf16x8;
typedef __attribute__((ext_vector_type(4))) float floatx4;

__device__ __forceinline__ unsigned short f2bf(float f) {   // RNE fp32->bf16
    unsigned int u = __float_as_uint(f);
    u += 0x7fffu + ((u >> 16) & 1u);
    return (unsigned short)(u >> 16);
}
__device__ __forceinline__ float bf2f(unsigned short s) {
    return __uint_as_float(((unsigned int)s) << 16);
}
__device__ __forceinline__ float rcpf(float x) {
    float r;
    asm("v_rcp_f32 %0, %1" : "=v"(r) : "v"(x));
    return r;
}
__device__ __forceinline__ float fast_sigmoid(float x) {
    return rcpf(1.0f + __expf(-x));
}
__device__ __forceinline__ float fast_tanh(float x) {
    float e2 = __expf(-2.0f * fabsf(x));
    float t = (1.0f - e2) * rcpf(1.0f + e2);
    return copysignf(t, x);
}
__device__ __forceinline__ float leg_sigmoid(float x) { return 1.0f / (1.0f + __expf(-x)); }
__device__ __forceinline__ float leg_tanh(float x) {
    float e2 = __expf(-2.0f * fabsf(x));
    float t = (1.0f - e2) / (1.0f + e2);
    return copysignf(t, x);
}

// Compressed B-fragment pack (proven r6/r7): quad3 stored once as zero pad.
__global__ void prep_w_kernel(const float* __restrict__ Wc,
                              unsigned short* __restrict__ Wfrag) {
    int i = blockIdx.x * 256 + threadIdx.x;
    if (i >= WSH_PAD) return;
    if (i >= WSH) { Wfrag[i] = 0; return; }
    int j    = i & 7;
    int t8   = i >> 3;
    int lane = t8 % 48;
    int t48  = t8 / 48;
    int g    = t48 & 3;
    int tap  = t48 >> 2;
    int k    = ((lane >> 4) << 3) + j;
    int col  = lane & 15;
    int o    = g * 16 + col;
    float w  = 0.0f;
    if (k < 21) {
        int ci_ref = (k < 16) ? (5 + k) : (k - 16);
        w = Wc[(o * 21 + ci_ref) * 9 + tap];
    }
    Wfrag[i] = f2bf(w);
}

__global__ void prep_x_kernel(const float* __restrict__ x,
                              unsigned short* __restrict__ xp) {
    size_t n = (size_t)blockIdx.x * 256 + threadIdx.x;
    const size_t TOTPX = (size_t)BB * TT * HH * WW;
    if (n >= TOTPX) return;
    size_t bt  = n / (size_t)(HH * WW);
    size_t pix = n - bt * (size_t)(HH * WW);
    const float* src = x + bt * (size_t)CIN * HH * WW + pix;
    unsigned short v[8];
    #pragma unroll
    for (int c = 0; c < CIN; ++c) v[c] = f2bf(src[(size_t)c * HH * WW]);
    v[5] = 0; v[6] = 0; v[7] = 0;
    *(uint4*)&xp[n * 8] = *(const uint4*)v;
}

__global__ void prep_flags_kernel(unsigned int* __restrict__ flags) {
    int i = blockIdx.x * 256 + threadIdx.x;
    if (i < NTILES) flags[i] = 0;
}

// ---------------------------------------------------------------------------
// Temporal-blocked persistent kernel (Tb = 2). 1024 blocks x 256 thr,
// 4 blocks/CU (co-residency enforced by cooperative launch). Block owns
// tiles n0 = bid*2 and n0+1 (same batch/row, adjacent columns).
// Per visit (tile, super-step s):
//   stage S: h(2s-1) on 36x12 (halo 2) + x(2s); stage x(2s+1) into T
//   t0: compute h(2s),c(2s) on 34x10 -> h to LDS T, c to private ctmp
//   t1: compute h(2s+1),c(2s+1) on 32x8 -> h/c to global (ping-pong)
//   publish flag = s+1
// Global h exchanges: 6 instead of 12. Safety: 1-step buffer skew proven by
// flag>=s wait; every c/h global px written by exactly one owner per buffer.
// ---------------------------------------------------------------------------
__global__ __launch_bounds__(256, 4)
void convlstm_temporal_kernel(const unsigned short* __restrict__ xp,
                              unsigned short* __restrict__ ha,
                              unsigned short* __restrict__ hb,
                              float* __restrict__ c0,
                              float* __restrict__ c1,
                              float* __restrict__ ctmp,
                              const unsigned short* __restrict__ Wfrag,
                              const float* __restrict__ bias,
                              const float* __restrict__ Wf,
                              const float* __restrict__ bfin,
                              float* __restrict__ out,
                              unsigned int* __restrict__ flags) {
    __shared__ unsigned short sm[SMSH];   // S | T | zero | dump

    const int tid  = threadIdx.x;
    const int lane = tid & 63;
    const int wave = tid >> 6;            // 0..3
    const int u    = lane & 15;
    const int quad = lane >> 4;
    const int bid  = (int)blockIdx.x;

    const int n0  = bid * 2;
    const int bb  = n0 >> 8;
    const int rem = n0 & 255;
    const int ty  = rem >> 3;
    const int tx0 = rem & 7;
    const int y0  = ty * PTY;

    if (tid == 0) { uint4 z = {0, 0, 0, 0}; *(uint4*)&sm[ZOFF] = z; }

    // compressed W read base (lanes 48-63 -> shared zero block in the table)
    const unsigned short* wptr = (lane < 48) ? (Wfrag + lane * 8) : (Wfrag + WSH);
    const int wstep = (lane < 48) ? 384 : 0;

    // neighbor poll deltas (wave0 lanes 0..7)
    int nb_dy = 0, nb_dx = 0;
    {
        int s8 = lane + (lane >= 4 ? 1 : 0);
        nb_dy = s8 / 3 - 1;
        nb_dx = s8 - (s8 / 3) * 3 - 1;
    }

    // hoisted staging descriptors: S rows (tid, tid+256), T rows (tid, tid+256)
    int scol_[2], hby_[2], xby_[2];
    bool sv_[2], yos_[2];
    #pragma unroll
    for (int it = 0; it < 2; ++it) {
        int i = tid + it * 256;
        sv_[it] = (i < SNPX);
        int rr = i / SHX;
        scol_[it] = i - rr * SHX - 2;
        int gy = y0 + rr - 2;
        yos_[it] = ((unsigned)gy < (unsigned)HH);
        hby_[it] = (bb * HH * WW + gy * WW) * HIDDEN;
        xby_[it] = (bb * TT * HH * WW + gy * WW) * 8;
    }
    int tcolx_[2], xbyt_[2];
    bool tv_[2], yot_[2];
    #pragma unroll
    for (int it = 0; it < 2; ++it) {
        int j = tid + it * 256;
        tv_[it] = (j < TNPX);
        int rr = j / THX;
        tcolx_[it] = j - rr * THX - 1;
        int gy = y0 + rr - 1;
        yot_[it] = ((unsigned)gy < (unsigned)HH);
        xbyt_[it] = (bb * TT * HH * WW + gy * WW) * 8;
    }

    float bg[4];
    #pragma unroll
    for (int g = 0; g < 4; ++g) bg[g] = bias[g * 16 + u];
    const float wfu = Wf[u];
    const float bf0 = bfin[0];

    #pragma unroll 1
    for (int s = 0; s < NSS; ++s) {
        const unsigned short* h_in = (s & 1) ? ha : hb;
        unsigned short* h_out      = (s & 1) ? hb : ha;
        const float* c_prev = (s & 1) ? c0 : c1;
        float* c_cur        = (s & 1) ? c1 : c0;
        const int first  = (s == 0);
        const int lastss = (s == NSS - 1);

        #pragma unroll 1
        for (int v = 0; v < 2; ++v) {
            const int n  = n0 + v;
            const int tx = tx0 + v;
            const int x0 = tx * PTX;

            // ---- (A) wait: 8 neighbors finished super-step s-1 ----
            if (s > 0) {
                if (wave == 0) {
                    bool act = (lane < 8)
                        && ((unsigned)(tx + nb_dx) < 8u)
                        && ((unsigned)(ty + nb_dy) < 32u);
                    int nb = n + nb_dy * 8 + nb_dx;
                    for (;;) {
                        unsigned fv = act
                            ? __hip_atomic_load(&flags[nb], __ATOMIC_RELAXED,
                                                __HIP_MEMORY_SCOPE_AGENT)
                            : 0xFFFFFFFFu;
                        if (__all(fv >= (unsigned)s)) break;
                        __builtin_amdgcn_s_sleep(2);
                    }
                    if (tid == 0) __threadfence();   // acquire
                }
                __syncthreads();
            }

            // ---- (B) stage S: h(2s-1) + x(2s); stage T: x(2s+1) ----
            #pragma unroll
            for (int it = 0; it < 2; ++it) {
                if (sv_[it]) {
                    unsigned short* rp = &sm[(tid + it * 256) * RS];
                    uint4 z = {0, 0, 0, 0};
                    int gx = x0 + scol_[it];
                    bool inb = yos_[it] && ((unsigned)gx < (unsigned)WW);
                    if (inb && !first) {
                        const unsigned short* hp = h_in + hby_[it] + gx * HIDDEN;
                        *(uint4*)&rp[0] = *(const uint4*)&hp[0];
                        *(uint4*)&rp[8] = *(const uint4*)&hp[8];
                    } else {
                        *(uint4*)&rp[0] = z; *(uint4*)&rp[8] = z;
                    }
                    if (inb)
                        *(uint4*)&rp[16] =
                            *(const uint4*)&xp[xby_[it] + (2 * s) * XSTEP + gx * 8];
                    else
                        *(uint4*)&rp[16] = z;
                }
            }
            #pragma unroll
            for (int it = 0; it < 2; ++it) {
                if (tv_[it]) {
                    unsigned short* rp = &sm[T_OFF + (tid + it * 256) * RS];
                    uint4 z = {0, 0, 0, 0};
                    int gx = x0 + tcolx_[it];
                    bool inb = yot_[it] && ((unsigned)gx < (unsigned)WW);
                    if (inb)
                        *(uint4*)&rp[16] =
                            *(const uint4*)&xp[xbyt_[it] + (2 * s + 1) * XSTEP + gx * 8];
                    else
                        *(uint4*)&rp[16] = z;
                }
            }
            __syncthreads();

            // ---- (C) t0: 30 M-tiles on 34x10 (3 bands x 10 rows) ----
            #pragma unroll 1
            for (int k = 0; k < 8; ++k) {
                int idx = wave + (k << 2);
                if (idx >= 30) break;              // wave-uniform
                int rq   = idx / 3;
                int band = idx - rq * 3;
                int row  = rq - 1;                 // -1..8
                int col0 = band * 16 - 1;          // -1, 15, 31
                int acol = col0 + u;
                bool aval = (acol <= 32);          // output cols needed <= 32
                int A0, tmul;
                if (quad < 3 && aval) {
                    A0 = ((row + 1) * SHX + (acol + 1)) * RS + quad * 8;
                    tmul = RS;
                } else { A0 = ZOFF; tmul = 0; }

                floatx4 acc[4];
                #pragma unroll
                for (int g = 0; g < 4; ++g)
                    acc[g] = (floatx4){bg[g], bg[g], bg[g], bg[g]};

                #pragma unroll 3
                for (int tap = 0; tap < 9; ++tap) {
                    int ky = tap / 3;
                    int kx = tap - ky * 3;
                    bf16x8 bfr[4];
                    #pragma unroll
                    for (int g = 0; g < 4; ++g)
                        bfr[g] = *(const bf16x8*)&wptr[(tap * 4 + g) * wstep];
                    bf16x8 af = *(const bf16x8*)&sm[A0 + (ky * SHX + kx) * tmul];
                    #pragma unroll
                    for (int g = 0; g < 4; ++g)
                        acc[g] = __builtin_amdgcn_mfma_f32_16x16x32_bf16(
                            af, bfr[g], acc[g], 0, 0, 0);
                }

                int gy = y0 + row;
                bool yin = ((unsigned)gy < (unsigned)HH);
                #pragma unroll
                for (int r = 0; r < 4; ++r) {
                    int tcol = col0 + quad * 4 + r;
                    bool cval = (tcol <= 32);
                    int gx = x0 + tcol;
                    bool inb = yin && ((unsigned)gx < (unsigned)WW);
                    float ig = fast_sigmoid(acc[0][r]);
                    float fg = fast_sigmoid(acc[1][r]);
                    float og = fast_sigmoid(acc[2][r]);
                    float gg = fast_tanh(acc[3][r]);
                    float c_old = 0.0f;
                    if (!first && inb && cval)
                        c_old = c_prev[(bb * HH * WW + gy * WW + gx) * HIDDEN + u];
                    float c_new = fg * c_old + ig * gg;
                    if (cval)
                        ctmp[bid * (TNPX * HIDDEN)
                             + ((row + 1) * THX + tcol + 1) * HIDDEN + u] = c_new;
                    unsigned short hs = inb ? f2bf(og * fast_tanh(c_new))
                                            : (unsigned short)0;
                    int tw = cval ? (T_OFF + ((row + 1) * THX + tcol + 1) * RS + u)
                                  : (DOFF + u);
                    sm[tw] = hs;
                }
            }
            __syncthreads();   // T complete; ctmp stores drained (vmcnt)

            // ---- (D) t1: 16 M-tiles on 32x8 (r0 scheme over region T) ----
            #pragma unroll 1
            for (int half = 0; half < 2; ++half) {
                floatx4 acc[2][4];
                int A[2];
                #pragma unroll
                for (int mh = 0; mh < 2; ++mh) {
                    int m   = wave + (half * 2 + mh) * 4;
                    int my  = m >> 1;
                    int mxx = (m & 1) << 4;
                    A[mh] = (quad < 3)
                        ? (T_OFF + (my * THX + mxx + u) * RS + quad * 8) : ZOFF;
                    #pragma unroll
                    for (int g = 0; g < 4; ++g)
                        acc[mh][g] = (floatx4){bg[g], bg[g], bg[g], bg[g]};
                }
                const int msel = (quad < 3) ? RS : 0;

                #pragma unroll 3
                for (int tap = 0; tap < 9; ++tap) {
                    int ky = tap / 3;
                    int kx = tap - ky * 3;
                    int toff = (ky * THX + kx) * msel;
                    bf16x8 bfr[4];
                    #pragma unroll
                    for (int g = 0; g < 4; ++g)
                        bfr[g] = *(const bf16x8*)&wptr[(tap * 4 + g) * wstep];
                    #pragma unroll
                    for (int mh = 0; mh < 2; ++mh) {
                        bf16x8 af = *(const bf16x8*)&sm[A[mh] + toff];
                        #pragma unroll
                        for (int g = 0; g < 4; ++g)
                            acc[mh][g] = __builtin_amdgcn_mfma_f32_16x16x32_bf16(
                                af, bfr[g], acc[mh][g], 0, 0, 0);
                    }
                }

                #pragma unroll
                for (int mh = 0; mh < 2; ++mh) {
                    int m   = wave + (half * 2 + mh) * 4;
                    int my  = m >> 1;
                    int mxx = (m & 1) << 4;
                    int py  = y0 + my;
                    #pragma unroll
                    for (int r = 0; r < 4; ++r) {
                        int cl  = mxx + quad * 4 + r;
                        int pxx = x0 + cl;
                        float ig = fast_sigmoid(acc[mh][0][r]);
                        float fg = fast_sigmoid(acc[mh][1][r]);
                        float og = fast_sigmoid(acc[mh][2][r]);
                        float gg = fast_tanh(acc[mh][3][r]);
                        float c_old = ctmp[bid * (TNPX * HIDDEN)
                                           + ((my + 1) * THX + cl + 1) * HIDDEN + u];
                        float c_new = fg * c_old + ig * gg;
                        size_t gidx = ((size_t)bb * HH * WW + (size_t)py * WW + pxx)
                                      * HIDDEN + u;
                        float hval = og * fast_tanh(c_new);
                        if (lastss) {
                            float sred = wfu * hval;
                            sred += __shfl_xor(sred, 1);
                            sred += __shfl_xor(sred, 2);
                            sred += __shfl_xor(sred, 4);
                            sred += __shfl_xor(sred, 8);
                            if (u == 0)
                                out[(size_t)bb * HH * WW + (size_t)py * WW + pxx]
                                    = sred + bf0;
                        } else {
                            c_cur[gidx] = c_new;
                            h_out[gidx] = f2bf(hval);
                        }
                    }
                }
            }

            // ---- (E) end-of-visit barrier + publish ----
            __syncthreads();
            if (!lastss && tid == 0) {
                __threadfence();   // release
                __hip_atomic_store(&flags[n], (unsigned)(s + 1), __ATOMIC_RELAXED,
                                   __HIP_MEMORY_SCOPE_AGENT);
            }
        }
    }
}

// ---------------------------------------------------------------------------
// Legacy per-step path (round-0 structure, compressed W) — fallback.
// ---------------------------------------------------------------------------
__global__ __launch_bounds__(256, 5)
void convlstm_step_kernel(const float* __restrict__ x, int t,
                          const unsigned short* __restrict__ xp,
                          const unsigned short* __restrict__ h_in,
                          unsigned short* __restrict__ h_out,
                          float* __restrict__ c_state,
                          const unsigned short* __restrict__ Wfrag,
                          const float* __restrict__ bias,
                          int first, int use_xp) {
    __shared__ unsigned short tile[NPX * STRIDE];

    const int tid  = threadIdx.x;
    const int lane = tid & 63;
    const int wave = tid >> 6;
    const int x0 = blockIdx.x * TX;
    const int y0 = blockIdx.y * TY;
    const int bb = blockIdx.z;

    for (int i = tid; i < NPX; i += 256) {
        int ly = i / HALO_X;
        int lx = i - ly * HALO_X;
        int gy = y0 + ly - 1;
        int gx = x0 + lx - 1;
        bool inb = (gy >= 0 && gy < HH && gx >= 0 && gx < WW);
        unsigned short* row = &tile[i * STRIDE];
        uint4 z = {0, 0, 0, 0};
        if (inb && !first) {
            size_t hbase = ((size_t)bb * HH * WW + (size_t)gy * WW + gx) * HIDDEN;
            *(uint4*)&row[0] = *(const uint4*)&h_in[hbase];
            *(uint4*)&row[8] = *(const uint4*)&h_in[hbase + 8];
        } else {
            *(uint4*)&row[0] = z;
            *(uint4*)&row[8] = z;
        }
        if (use_xp) {
            if (inb) {
                size_t xb = (((size_t)bb * TT + t) * (size_t)(HH * WW)
                             + (size_t)gy * WW + gx) * 8;
                *(uint4*)&row[16] = *(const uint4*)&xp[xb];
            } else {
                *(uint4*)&row[16] = z;
            }
        } else {
            #pragma unroll
            for (int ci = 0; ci < CIN; ++ci) {
                float v = 0.0f;
                if (inb) v = x[(((size_t)bb * TT + t) * CIN + ci) * (size_t)(HH * WW)
                               + (size_t)gy * WW + gx];
                row[16 + ci] = f2bf(v);
            }
            row[21] = 0; row[22] = 0; row[23] = 0;
        }
        *(uint4*)&row[24] = z;
    }
    __syncthreads();

    const int u    = lane & 15;
    const int quad = lane >> 4;

    const unsigned short* wptr = (lane < 48) ? (Wfrag + lane * 8) : (Wfrag + WSH);
    const int wstep2 = (lane < 48) ? 384 : 0;

    float bg[4];
    #pragma unroll
    for (int g = 0; g < 4; ++g) bg[g] = bias[g * 16 + u];

    #pragma unroll 1
    for (int half = 0; half < 2; ++half) {
        floatx4 acc[2][4];
        int abase[2];
        #pragma unroll
        for (int mh = 0; mh < 2; ++mh) {
            int ml = half * 2 + mh;
            int m  = wave + ml * 4;
            int my = m >> 1;
            int mx = (m & 1) << 4;
            abase[mh] = (my * HALO_X + mx + u) * STRIDE + quad * 8;
            #pragma unroll
            for (int g = 0; g < 4; ++g)
                acc[mh][g] = (floatx4){bg[g], bg[g], bg[g], bg[g]};
        }

        #pragma unroll 3
        for (int tap = 0; tap < 9; ++tap) {
            int ky = tap / 3;
            int kx = tap - ky * 3;
            int toff = (ky * HALO_X + kx) * STRIDE;
            bf16x8 bfr[4];
            #pragma unroll
            for (int g = 0; g < 4; ++g)
                bfr[g] = *(const bf16x8*)&wptr[(tap * 4 + g) * wstep2];
            #pragma unroll
            for (int mh = 0; mh < 2; ++mh) {
                bf16x8 af = *(const bf16x8*)&tile[abase[mh] + toff];
                #pragma unroll
                for (int g = 0; g < 4; ++g)
                    acc[mh][g] = __builtin_amdgcn_mfma_f32_16x16x32_bf16(
                        af, bfr[g], acc[mh][g], 0, 0, 0);
            }
        }

        #pragma unroll
        for (int mh = 0; mh < 2; ++mh) {
            int ml = half * 2 + mh;
            int m  = wave + ml * 4;
            int my = m >> 1;
            int mx = (m & 1) << 4;
            int py = y0 + my;
            #pragma unroll
            for (int r = 0; r < 4; ++r) {
                int pxx = x0 + mx + quad * 4 + r;
                size_t idx = ((size_t)bb * HH * WW + (size_t)py * WW + pxx) * HIDDEN + u;
                float ig = leg_sigmoid(acc[mh][0][r]);
                float fg = leg_sigmoid(acc[mh][1][r]);
                float og = leg_sigmoid(acc[mh][2][r]);
                float gg = leg_tanh(acc[mh][3][r]);
                float c_old = first ? 0.0f : c_state[idx];
                float c_new = fg * c_old + ig * gg;
                c_state[idx] = c_new;
                h_out[idx] = f2bf(og * leg_tanh(c_new));
            }
        }
    }
}

__global__ void final_conv_kernel(const unsigned short* __restrict__ h,
                                  const float* __restrict__ Wf,
                                  const float* __restrict__ bf_,
                                  float* __restrict__ out) {
    int i = blockIdx.x * 256 + threadIdx.x;
    if (i >= BB * HH * WW) return;
    size_t base = (size_t)i * HIDDEN;
    uint4 v0 = *(const uint4*)&h[base];
    uint4 v1 = *(const uint4*)&h[base + 8];
    const unsigned short* p0 = (const unsigned short*)&v0;
    const unsigned short* p1 = (const unsigned short*)&v1;
    float s = bf_[0];
    #pragma unroll
    for (int k = 0; k < 8; ++k) s += Wf[k] * bf2f(p0[k]);
    #pragma unroll
    for (int k = 0; k < 8; ++k) s += Wf[8 + k] * bf2f(p1[k]);
    out[i] = s;
}

extern "C" void kernel_launch(void* const* d_in, const int* in_sizes, int n_in,
                              void* d_out, int out_size, void* d_ws, size_t ws_size,
                              hipStream_t stream) {
    const float* x  = (const float*)d_in[0];
    const float* Wc = (const float*)d_in[1];
    const float* bc = (const float*)d_in[2];
    const float* Wf = (const float*)d_in[3];
    const float* bf = (const float*)d_in[4];
    float* out = (float*)d_out;

    char* ws = (char*)d_ws;
    const size_t h_bytes  = (size_t)BB * HH * WW * HIDDEN * 2;     // 16.78 MB
    const size_t c_bytes  = (size_t)BB * HH * WW * HIDDEN * 4;     // 33.55 MB
    const size_t ct_bytes = (size_t)NBLK * TNPX * HIDDEN * 4;      // 22.28 MB
    const size_t w_bytes  = (size_t)WSH_PAD * 2;                   // 27.7 KB
    const size_t f_bytes  = (size_t)NTILES * 4;                    // 8 KB
    const size_t x_bytes  = (size_t)BB * TT * HH * WW * 8 * 2;     // 100.7 MB

    // ---- temporal layout ----
    unsigned short* h_a  = (unsigned short*)(ws);
    unsigned short* h_b  = (unsigned short*)(ws + h_bytes);
    float* c0p           = (float*)(ws + 2 * h_bytes);
    float* c1p           = (float*)(ws + 2 * h_bytes + c_bytes);
    float* ctmp          = (float*)(ws + 2 * h_bytes + 2 * c_bytes);
    unsigned short* Wfr  = (unsigned short*)(ws + 2 * h_bytes + 2 * c_bytes + ct_bytes);
    unsigned int* flags  = (unsigned int*)(ws + 2 * h_bytes + 2 * c_bytes + ct_bytes + w_bytes);
    unsigned short* xp   = (unsigned short*)(ws + 2 * h_bytes + 2 * c_bytes + ct_bytes
                                             + w_bytes + f_bytes);
    const size_t need_temporal =
        2 * h_bytes + 2 * c_bytes + ct_bytes + w_bytes + f_bytes + x_bytes;  // ~224 MB

    bool done = false;
    if (ws_size >= need_temporal) {
        prep_w_kernel<<<(WSH_PAD + 255) / 256, 256, 0, stream>>>(Wc, Wfr);
        prep_flags_kernel<<<(NTILES + 255) / 256, 256, 0, stream>>>(flags);
        size_t totpx = (size_t)BB * TT * HH * WW;
        prep_x_kernel<<<(int)((totpx + 255) / 256), 256, 0, stream>>>(x, xp);

        int occ = 0;
        hipOccupancyMaxActiveBlocksPerMultiprocessor(&occ, convlstm_temporal_kernel,
                                                     256, 0);
        if (occ >= 4) {
            void* kargs[] = {
                (void*)&xp, (void*)&h_a, (void*)&h_b, (void*)&c0p, (void*)&c1p,
                (void*)&ctmp, (void*)&Wfr, (void*)&bc, (void*)&Wf, (void*)&bf,
                (void*)&out, (void*)&flags
            };
            if (hipLaunchCooperativeKernel((const void*)convlstm_temporal_kernel,
                                           dim3(NBLK, 1, 1), dim3(256, 1, 1),
                                           kargs, 0, stream) == hipSuccess)
                done = true;
        }
    }

    if (!done) {
        // ---- legacy compact layout ----
        unsigned short* lh_a = (unsigned short*)(ws);
        unsigned short* lh_b = (unsigned short*)(ws + h_bytes);
        float* lc            = (float*)(ws + 2 * h_bytes);
        unsigned short* lWfr = (unsigned short*)(ws + 2 * h_bytes + c_bytes);
        unsigned short* lxp  = (unsigned short*)(ws + 2 * h_bytes + c_bytes + w_bytes);
        const int use_xp =
            (ws_size >= 2 * h_bytes + c_bytes + w_bytes + x_bytes) ? 1 : 0;

        prep_w_kernel<<<(WSH_PAD + 255) / 256, 256, 0, stream>>>(Wc, lWfr);
        if (use_xp) {
            size_t totpx = (size_t)BB * TT * HH * WW;
            prep_x_kernel<<<(int)((totpx + 255) / 256), 256, 0, stream>>>(x, lxp);
        }

        dim3 grid(WW / TX, HH / TY, BB);
        dim3 block(256, 1, 1);
        const unsigned short* h_in = lh_a;
        for (int t = 0; t < TT; ++t) {
            unsigned short* h_out = (t & 1) ? lh_b : lh_a;
            convlstm_step_kernel<<<grid, block, 0, stream>>>(
                x, t, use_xp ? lxp : (const unsigned short*)0,
                h_in, h_out, lc, lWfr, bc, (t == 0) ? 1 : 0, use_xp);
            h_in = h_out;
        }
        final_conv_kernel<<<(BB * HH * WW + 255) / 256, 256, 0, stream>>>(
            h_in, Wf, bf, out);
    }
}

// Round 10
// 685.827 us; speedup vs baseline: 1.1078x; 1.1078x over previous
//
#include <hip/hip_runtime.h>
#include <math.h>

#define HIDDEN 16
#define CIN 5
#define BB 8
#define TT 12
#define HH 256
#define WW 256
// legacy (per-step fallback) tile geometry
#define TX 32
#define TY 8
#define HALO_X 34
#define HALO_Y 10
#define NPX (HALO_X * HALO_Y)
#define STRIDE 40
// W-in-registers persistent geometry: 64x8 tiles, 2 per block, 512 blocks
#define PTX 64
#define PTY 8
#define PHX 66
#define PHY 10
#define PNPX (PHX * PHY)        // 660 staged pixels
#define ROWSH 28                // h16|x8|pad4 -> 56 B; bank stride 14, 2-way free
#define ZOFF (PNPX * ROWSH)     // zero block for quad3 K-pad reads
#define SMSH (ZOFF + 8)         // 18488 shorts = 36976 B -> 2 blocks/CU easily
#define NTILES 1024
#define NBLK 512                // 2 blocks/CU x 256 CU, 2 tiles each
#define XSTEP (HH * WW * 8)
#define WTAB (9 * 4 * 64 * 8)   // full B-fragment table (r0 layout)

typedef __attribute__((ext_vector_type(8))) short bf16x8;
typedef __attribute__((ext_vector_type(4))) float floatx4;

__device__ __forceinline__ unsigned short f2bf(float f) {   // RNE fp32->bf16
    unsigned int u = __float_as_uint(f);
    u += 0x7fffu + ((u >> 16) & 1u);
    return (unsigned short)(u >> 16);
}
__device__ __forceinline__ float bf2f(unsigned short s) {
    return __uint_as_float(((unsigned int)s) << 16);
}
__device__ __forceinline__ float rcpf(float x) {
    float r;
    asm("v_rcp_f32 %0, %1" : "=v"(r) : "v"(x));
    return r;
}
__device__ __forceinline__ float fast_sigmoid(float x) {
    return rcpf(1.0f + __expf(-x));
}
__device__ __forceinline__ float fast_tanh(float x) {
    float e2 = __expf(-2.0f * fabsf(x));
    float t = (1.0f - e2) * rcpf(1.0f + e2);
    return copysignf(t, x);
}
__device__ __forceinline__ float leg_sigmoid(float x) { return 1.0f / (1.0f + __expf(-x)); }
__device__ __forceinline__ float leg_tanh(float x) {
    float e2 = __expf(-2.0f * fabsf(x));
    float t = (1.0f - e2) / (1.0f + e2);
    return copysignf(t, x);
}

// Full B-fragment table (r0 layout, proven): Wfrag[tap][gate][lane][j];
// lane holds B[k=(lane>>4)*8+j][col=lane&15]; k>=21 zero (incl. all quad3).
__global__ void prep_w_kernel(const float* __restrict__ Wc,
                              unsigned short* __restrict__ Wfrag) {
    int i = blockIdx.x * 256 + threadIdx.x;
    if (i >= WTAB) return;
    int j    = i & 7;
    int lane = (i >> 3) & 63;
    int g    = (i >> 9) & 3;
    int tap  = i >> 11;
    int k    = ((lane >> 4) << 3) + j;
    int col  = lane & 15;
    int o    = g * 16 + col;
    float w  = 0.0f;
    if (k < 21) {
        int ci_ref = (k < 16) ? (5 + k) : (k - 16);
        w = Wc[(o * 21 + ci_ref) * 9 + tap];
    }
    Wfrag[i] = f2bf(w);
}

__global__ void prep_x_kernel(const float* __restrict__ x,
                              unsigned short* __restrict__ xp) {
    size_t n = (size_t)blockIdx.x * 256 + threadIdx.x;
    const size_t TOTPX = (size_t)BB * TT * HH * WW;
    if (n >= TOTPX) return;
    size_t bt  = n / (size_t)(HH * WW);
    size_t pix = n - bt * (size_t)(HH * WW);
    const float* src = x + bt * (size_t)CIN * HH * WW + pix;
    unsigned short v[8];
    #pragma unroll
    for (int c = 0; c < CIN; ++c) v[c] = f2bf(src[(size_t)c * HH * WW]);
    v[5] = 0; v[6] = 0; v[7] = 0;
    *(uint4*)&xp[n * 8] = *(const uint4*)v;
}

__global__ void prep_flags_kernel(unsigned int* __restrict__ flags) {
    int i = blockIdx.x * 256 + threadIdx.x;
    if (i < NTILES) flags[i] = 0;
}

// ---------------------------------------------------------------------------
// W-in-REGISTERS persistent kernel. 512 blocks x 256 thr, 2 blocks/CU
// (cooperative launch enforces co-residency). Each thread loads its 36
// B-fragments (144 VGPRs) ONCE; the inner loop is 18 af LDS reads + 72 MFMAs
// per half -- no per-visit W re-fetch (the 9-round invariant cost).
// Block owns tiles n0=bid*2, n0+1 (same batch/row, adjacent cols).
// c in global fp32 (r0-style in-place, per-px exclusive owner).
// Flags protocol verbatim from r7 (proven). Fused final 1x1 at t==TT-1.
// ---------------------------------------------------------------------------
__global__ __launch_bounds__(256, 2)
void convlstm_wreg_kernel(const unsigned short* __restrict__ xp,
                          unsigned short* __restrict__ ha,
                          unsigned short* __restrict__ hb,
                          float* __restrict__ c_state,
                          const unsigned short* __restrict__ Wfrag,
                          const float* __restrict__ bias,
                          const float* __restrict__ Wf,
                          const float* __restrict__ bfin,
                          float* __restrict__ out,
                          unsigned int* __restrict__ flags) {
    __shared__ unsigned short sm[SMSH];   // one 66x10 tile region | zero block

    const int tid  = threadIdx.x;
    const int lane = tid & 63;
    const int wave = tid >> 6;            // 0..3
    const int u    = lane & 15;
    const int quad = lane >> 4;
    const int bid  = (int)blockIdx.x;

    // tiles: per batch 4 cols x 32 rows (128); n0 even -> v=0,1 same row
    const int n0  = bid * 2;
    const int bb  = n0 >> 7;
    const int rem = n0 & 127;
    const int ty  = rem >> 2;
    const int tx0 = rem & 3;
    const int y0  = ty * PTY;

    // ---- one-time: all 36 B-fragments into registers (static indexing) ----
    bf16x8 wreg[36];
    #pragma unroll
    for (int i = 0; i < 36; ++i)
        wreg[i] = *(const bf16x8*)&Wfrag[(size_t)(i * 64 + lane) * 8];

    if (tid == 0) { uint4 z = {0, 0, 0, 0}; *(uint4*)&sm[ZOFF] = z; }

    // neighbor poll deltas (wave0 lanes 0..7)
    int nb_dy = 0, nb_dx = 0;
    {
        int s8 = lane + (lane >= 4 ? 1 : 0);
        nb_dy = s8 / 3 - 1;
        nb_dx = s8 - (s8 / 3) * 3 - 1;
    }

    // staging descriptors: rows tid, tid+256, tid+512 (third: tid < 148)
    int scol[3], hby[3], xby[3];
    bool sval[3], yok[3];
    #pragma unroll
    for (int it = 0; it < 3; ++it) {
        int i = tid + it * 256;
        sval[it] = (i < PNPX);
        int ly = i / PHX;
        int lx = i - ly * PHX;
        int gy = y0 + ly - 1;
        yok[it]  = ((unsigned)gy < (unsigned)HH);
        scol[it] = lx - 1;
        hby[it]  = (bb * HH * WW + gy * WW) * HIDDEN;
        xby[it]  = (bb * TT * HH * WW + gy * WW) * 8;
    }

    float bg[4];
    #pragma unroll
    for (int g = 0; g < 4; ++g) bg[g] = bias[g * 16 + u];
    const float wfu = Wf[u];
    const float bf0 = bfin[0];
    const int msel  = (quad < 3) ? ROWSH : 0;

    #pragma unroll 1
    for (int t = 0; t < TT; ++t) {
        const unsigned short* h_in = (t & 1) ? ha : hb;
        unsigned short* h_out      = (t & 1) ? hb : ha;
        const int first = (t == 0);
        const int last  = (t == TT - 1);

        #pragma unroll 1
        for (int v = 0; v < 2; ++v) {
            const int n  = n0 + v;
            const int tx = tx0 + v;
            const int x0 = tx * PTX;

            // ---- (A) wait: 8 neighbors finished step t-1 ----
            if (t > 0) {
                if (wave == 0) {
                    bool act = (lane < 8)
                        && ((unsigned)(tx + nb_dx) < 4u)
                        && ((unsigned)(ty + nb_dy) < 32u);
                    int nb = n + nb_dy * 4 + nb_dx;
                    for (;;) {
                        unsigned fv = act
                            ? __hip_atomic_load(&flags[nb], __ATOMIC_RELAXED,
                                                __HIP_MEMORY_SCOPE_AGENT)
                            : 0xFFFFFFFFu;
                        if (__all(fv >= (unsigned)t)) break;
                        __builtin_amdgcn_s_sleep(2);
                    }
                    if (tid == 0) __threadfence();   // acquire
                }
                __syncthreads();
            }

            // ---- (B) stage 660-px halo: h(t-1) + x(t) ----
            #pragma unroll
            for (int it = 0; it < 3; ++it) {
                if (sval[it]) {
                    unsigned short* rp = &sm[(tid + it * 256) * ROWSH];
                    uint4 z = {0, 0, 0, 0};
                    int gx = x0 + scol[it];
                    bool inb = yok[it] && ((unsigned)gx < (unsigned)WW);
                    if (inb && !first) {
                        const unsigned short* hp = h_in + hby[it] + gx * HIDDEN;
                        *(uint4*)&rp[0] = *(const uint4*)&hp[0];
                        *(uint4*)&rp[8] = *(const uint4*)&hp[8];
                    } else {
                        *(uint4*)&rp[0] = z; *(uint4*)&rp[8] = z;
                    }
                    if (inb)
                        *(uint4*)&rp[16] =
                            *(const uint4*)&xp[xby[it] + t * XSTEP + gx * 8];
                    else
                        *(uint4*)&rp[16] = z;
                }
            }
            __syncthreads();

            // ---- (C) compute: 4 halves x 2 M-tiles; W from registers ----
            #pragma unroll 1
            for (int hh = 0; hh < 4; ++hh) {
                floatx4 acc[2][4];
                int A[2];
                #pragma unroll
                for (int mh = 0; mh < 2; ++mh) {
                    int m   = wave * 8 + hh * 2 + mh;   // 0..31
                    int my  = m >> 2;
                    int mxt = m & 3;
                    A[mh] = (quad < 3)
                        ? ((my * PHX + mxt * 16 + u) * ROWSH + quad * 8) : ZOFF;
                    #pragma unroll
                    for (int g = 0; g < 4; ++g)
                        acc[mh][g] = (floatx4){bg[g], bg[g], bg[g], bg[g]};
                }

                #pragma unroll
                for (int tap = 0; tap < 9; ++tap) {
                    int ktap = (tap / 3) * PHX + (tap % 3);
                    #pragma unroll
                    for (int mh = 0; mh < 2; ++mh) {
                        bf16x8 af = *(const bf16x8*)&sm[A[mh] + ktap * msel];
                        #pragma unroll
                        for (int g = 0; g < 4; ++g)
                            acc[mh][g] = __builtin_amdgcn_mfma_f32_16x16x32_bf16(
                                af, wreg[tap * 4 + g], acc[mh][g], 0, 0, 0);
                    }
                }

                // ---- epilogue: gates + global c r/w + stores ----
                #pragma unroll
                for (int mh = 0; mh < 2; ++mh) {
                    int m   = wave * 8 + hh * 2 + mh;
                    int my  = m >> 2;
                    int mxt = m & 3;
                    int py  = y0 + my;
                    int col0 = mxt * 16 + quad * 4;
                    size_t gidx0 = ((size_t)bb * HH * WW + (size_t)py * WW + x0 + col0)
                                   * HIDDEN + u;
                    #pragma unroll
                    for (int r = 0; r < 4; ++r) {
                        float ig = fast_sigmoid(acc[mh][0][r]);
                        float fg = fast_sigmoid(acc[mh][1][r]);
                        float og = fast_sigmoid(acc[mh][2][r]);
                        float gg = fast_tanh(acc[mh][3][r]);
                        size_t gidx = gidx0 + (size_t)r * HIDDEN;
                        float c_old = first ? 0.0f : c_state[gidx];
                        float c_new = fg * c_old + ig * gg;
                        float hval = og * fast_tanh(c_new);
                        if (last) {
                            // fused 1x1 conv: sum over 16 channels (u lanes)
                            float sred = wfu * hval;
                            sred += __shfl_xor(sred, 1);
                            sred += __shfl_xor(sred, 2);
                            sred += __shfl_xor(sred, 4);
                            sred += __shfl_xor(sred, 8);
                            if (u == 0)
                                out[(size_t)bb * HH * WW + (size_t)py * WW
                                    + x0 + col0 + r] = sred + bf0;
                        } else {
                            c_state[gidx] = c_new;
                            h_out[gidx] = f2bf(hval);
                        }
                    }
                }
            }

            // ---- (E) end-of-visit barrier + publish ----
            __syncthreads();   // LDS reads done; drains vmcnt before barrier
            if (!last && tid == 0) {
                __threadfence();   // release
                __hip_atomic_store(&flags[n], (unsigned)(t + 1), __ATOMIC_RELAXED,
                                   __HIP_MEMORY_SCOPE_AGENT);
            }
        }
    }
}

// ---------------------------------------------------------------------------
// Legacy per-step path (round-0, proven at ~696 us) — fallback.
// ---------------------------------------------------------------------------
__global__ __launch_bounds__(256, 5)
void convlstm_step_kernel(const float* __restrict__ x, int t,
                          const unsigned short* __restrict__ xp,
                          const unsigned short* __restrict__ h_in,
                          unsigned short* __restrict__ h_out,
                          float* __restrict__ c_state,
                          const unsigned short* __restrict__ Wfrag,
                          const float* __restrict__ bias,
                          int first, int use_xp) {
    __shared__ unsigned short tile[NPX * STRIDE];

    const int tid  = threadIdx.x;
    const int lane = tid & 63;
    const int wave = tid >> 6;
    const int x0 = blockIdx.x * TX;
    const int y0 = blockIdx.y * TY;
    const int bb = blockIdx.z;

    for (int i = tid; i < NPX; i += 256) {
        int ly = i / HALO_X;
        int lx = i - ly * HALO_X;
        int gy = y0 + ly - 1;
        int gx = x0 + lx - 1;
        bool inb = (gy >= 0 && gy < HH && gx >= 0 && gx < WW);
        unsigned short* row = &tile[i * STRIDE];
        uint4 z = {0, 0, 0, 0};
        if (inb && !first) {
            size_t hbase = ((size_t)bb * HH * WW + (size_t)gy * WW + gx) * HIDDEN;
            *(uint4*)&row[0] = *(const uint4*)&h_in[hbase];
            *(uint4*)&row[8] = *(const uint4*)&h_in[hbase + 8];
        } else {
            *(uint4*)&row[0] = z;
            *(uint4*)&row[8] = z;
        }
        if (use_xp) {
            if (inb) {
                size_t xb = (((size_t)bb * TT + t) * (size_t)(HH * WW)
                             + (size_t)gy * WW + gx) * 8;
                *(uint4*)&row[16] = *(const uint4*)&xp[xb];
            } else {
                *(uint4*)&row[16] = z;
            }
        } else {
            #pragma unroll
            for (int ci = 0; ci < CIN; ++ci) {
                float v = 0.0f;
                if (inb) v = x[(((size_t)bb * TT + t) * CIN + ci) * (size_t)(HH * WW)
                               + (size_t)gy * WW + gx];
                row[16 + ci] = f2bf(v);
            }
            row[21] = 0; row[22] = 0; row[23] = 0;
        }
        *(uint4*)&row[24] = z;
    }
    __syncthreads();

    const int u    = lane & 15;
    const int quad = lane >> 4;

    float bg[4];
    #pragma unroll
    for (int g = 0; g < 4; ++g) bg[g] = bias[g * 16 + u];

    #pragma unroll 1
    for (int half = 0; half < 2; ++half) {
        floatx4 acc[2][4];
        int abase[2];
        #pragma unroll
        for (int mh = 0; mh < 2; ++mh) {
            int ml = half * 2 + mh;
            int m  = wave + ml * 4;
            int my = m >> 1;
            int mx = (m & 1) << 4;
            abase[mh] = (my * HALO_X + mx + u) * STRIDE + quad * 8;
            #pragma unroll
            for (int g = 0; g < 4; ++g)
                acc[mh][g] = (floatx4){bg[g], bg[g], bg[g], bg[g]};
        }

        #pragma unroll 3
        for (int tap = 0; tap < 9; ++tap) {
            int ky = tap / 3;
            int kx = tap - ky * 3;
            int toff = (ky * HALO_X + kx) * STRIDE;
            bf16x8 bfr[4];
            #pragma unroll
            for (int g = 0; g < 4; ++g)
                bfr[g] = *(const bf16x8*)&Wfrag[(size_t)((tap * 4 + g) * 64 + lane) * 8];
            #pragma unroll
            for (int mh = 0; mh < 2; ++mh) {
                bf16x8 af = *(const bf16x8*)&tile[abase[mh] + toff];
                #pragma unroll
                for (int g = 0; g < 4; ++g)
                    acc[mh][g] = __builtin_amdgcn_mfma_f32_16x16x32_bf16(
                        af, bfr[g], acc[mh][g], 0, 0, 0);
            }
        }

        #pragma unroll
        for (int mh = 0; mh < 2; ++mh) {
            int ml = half * 2 + mh;
            int m  = wave + ml * 4;
            int my = m >> 1;
            int mx = (m & 1) << 4;
            int py = y0 + my;
            #pragma unroll
            for (int r = 0; r < 4; ++r) {
                int pxx = x0 + mx + quad * 4 + r;
                size_t idx = ((size_t)bb * HH * WW + (size_t)py * WW + pxx) * HIDDEN + u;
                float ig = leg_sigmoid(acc[mh][0][r]);
                float fg = leg_sigmoid(acc[mh][1][r]);
                float og = leg_sigmoid(acc[mh][2][r]);
                float gg = leg_tanh(acc[mh][3][r]);
                float c_old = first ? 0.0f : c_state[idx];
                float c_new = fg * c_old + ig * gg;
                c_state[idx] = c_new;
                h_out[idx] = f2bf(og * leg_tanh(c_new));
            }
        }
    }
}

__global__ void final_conv_kernel(const unsigned short* __restrict__ h,
                                  const float* __restrict__ Wf,
                                  const float* __restrict__ bf_,
                                  float* __restrict__ out) {
    int i = blockIdx.x * 256 + threadIdx.x;
    if (i >= BB * HH * WW) return;
    size_t base = (size_t)i * HIDDEN;
    uint4 v0 = *(const uint4*)&h[base];
    uint4 v1 = *(const uint4*)&h[base + 8];
    const unsigned short* p0 = (const unsigned short*)&v0;
    const unsigned short* p1 = (const unsigned short*)&v1;
    float s = bf_[0];
    #pragma unroll
    for (int k = 0; k < 8; ++k) s += Wf[k] * bf2f(p0[k]);
    #pragma unroll
    for (int k = 0; k < 8; ++k) s += Wf[8 + k] * bf2f(p1[k]);
    out[i] = s;
}

extern "C" void kernel_launch(void* const* d_in, const int* in_sizes, int n_in,
                              void* d_out, int out_size, void* d_ws, size_t ws_size,
                              hipStream_t stream) {
    const float* x  = (const float*)d_in[0];
    const float* Wc = (const float*)d_in[1];
    const float* bc = (const float*)d_in[2];
    const float* Wf = (const float*)d_in[3];
    const float* bf = (const float*)d_in[4];
    float* out = (float*)d_out;

    char* ws = (char*)d_ws;
    const size_t h_bytes = (size_t)BB * HH * WW * HIDDEN * 2;   // 16.78 MB
    const size_t c_bytes = (size_t)BB * HH * WW * HIDDEN * 4;   // 33.55 MB
    const size_t w_bytes = (size_t)WTAB * 2;                    // 36.9 KB
    const size_t f_bytes = (size_t)NTILES * 4;                  // 4 KB
    const size_t x_bytes = (size_t)BB * TT * HH * WW * 8 * 2;   // 100.7 MB

    unsigned short* h_a = (unsigned short*)(ws);
    unsigned short* h_b = (unsigned short*)(ws + h_bytes);
    float* c            = (float*)(ws + 2 * h_bytes);
    unsigned short* Wfr = (unsigned short*)(ws + 2 * h_bytes + c_bytes);
    unsigned int* flags = (unsigned int*)(ws + 2 * h_bytes + c_bytes + w_bytes);
    unsigned short* xp  = (unsigned short*)(ws + 2 * h_bytes + c_bytes + w_bytes + f_bytes);

    const int have_xp =
        (ws_size >= 2 * h_bytes + c_bytes + w_bytes + f_bytes + x_bytes) ? 1 : 0;

    prep_w_kernel<<<(WTAB + 255) / 256, 256, 0, stream>>>(Wc, Wfr);
    prep_flags_kernel<<<(NTILES + 255) / 256, 256, 0, stream>>>(flags);
    if (have_xp) {
        size_t totpx = (size_t)BB * TT * HH * WW;
        prep_x_kernel<<<(int)((totpx + 255) / 256), 256, 0, stream>>>(x, xp);
    }

    // Preferred path: W-in-registers persistent kernel (needs xp + 2/CU).
    bool done = false;
    if (have_xp) {
        int occ = 0;
        hipOccupancyMaxActiveBlocksPerMultiprocessor(&occ, convlstm_wreg_kernel,
                                                     256, 0);
        if (occ >= 2) {
            void* kargs[] = {
                (void*)&xp, (void*)&h_a, (void*)&h_b, (void*)&c,
                (void*)&Wfr, (void*)&bc, (void*)&Wf, (void*)&bf,
                (void*)&out, (void*)&flags
            };
            if (hipLaunchCooperativeKernel((const void*)convlstm_wreg_kernel,
                                           dim3(NBLK, 1, 1), dim3(256, 1, 1),
                                           kargs, 0, stream) == hipSuccess)
                done = true;
        }
    }

    if (!done) {
        // Legacy per-step path (round-0 behavior, proven)
        dim3 grid(WW / TX, HH / TY, BB);
        dim3 block(256, 1, 1);
        const unsigned short* h_in = h_a;
        for (int t = 0; t < TT; ++t) {
            unsigned short* h_out = (t & 1) ? h_b : h_a;
            convlstm_step_kernel<<<grid, block, 0, stream>>>(
                x, t, have_xp ? xp : (const unsigned short*)0,
                h_in, h_out, c, Wfr, bc, (t == 0) ? 1 : 0, have_xp);
            h_in = h_out;
        }
        final_conv_kernel<<<(BB * HH * WW + 255) / 256, 256, 0, stream>>>(
            h_in, Wf, bf, out);
    }
}